// Round 3
// baseline (233.805 us; speedup 1.0000x reference)
//
#include <hip/hip_runtime.h>

// Involution (B=8, H=W=192, C=64, G=4, K=3, R=4) — fused, round 3.
// R2 post-mortem: total parallelism capped at 18 waves/CU by the
// 1-pixel-per-thread Phase A (294912 px = 4608 waves total). Fix: 4 threads
// per pixel in Phase A (sub-split over the 16-d bottleneck and the 36-e kern
// outputs) -> 18432 waves = 72/CU of work, 32 resident. Phase B unchanged
// (quad-coalesced). LDS 13.3 KB, VGPR<=64 via __launch_bounds__(256,8).

#define B_   8
#define H_   192
#define W_   192
#define CR_  16
#define TH_  8
#define TW_  8
#define TILES_X (W_/TW_)                    // 24
#define TILES_PER_IMG (TILES_X*(H_/TH_))    // 576
#define NBLK (B_*TILES_PER_IMG)             // 4608
#define NPIX (TH_*TW_)                      // 64 pixels per block

constexpr float BN_EPS = 1e-3f;

template <bool INTERIOR>
__device__ __forceinline__ void phase_b(const float* __restrict__ x,
                                        float* __restrict__ out,
                                        const float4* __restrict__ s_kern,
                                        int img, int th0, int tw0, int tid)
{
    const int lane = tid & 63;
    const int wv   = tid >> 6;    // wave 0..3
    const int ploc = lane >> 4;   // quad member (pixel along w)
    const int c4i  = lane & 15;   // float4 channel chunk (g = 0..3 inside)
    const float* ximg = x + (((size_t)(img * H_ * W_)) << 6);
    float* oimg = out + (((size_t)(img * H_ * W_)) << 6);

    #pragma unroll
    for (int i = 0; i < 4; ++i) {
        const int Q   = wv * 4 + i;          // quad 0..15 in tile
        const int row = Q >> 1, qc = Q & 1;  // 8 rows x 2 quads/row
        const int h   = th0 + row;
        const int w   = tw0 + qc * 4 + ploc;
        const int px  = row * 8 + qc * 4 + ploc;
        const float4* kq = &s_kern[px * 9];

        float4 acc = make_float4(0.f, 0.f, 0.f, 0.f);
        #pragma unroll
        for (int ti = 0; ti < 3; ++ti) {
            int hh = h + ti - 1;
            bool vh = true;
            if (!INTERIOR) {
                vh = (unsigned)hh < (unsigned)H_;
                hh = hh < 0 ? 0 : (hh >= H_ ? H_ - 1 : hh);
            }
            #pragma unroll
            for (int tj = 0; tj < 3; ++tj) {
                int ww = w + tj - 1;
                bool valid = vh;
                if (!INTERIOR) {
                    valid = vh && ((unsigned)ww < (unsigned)W_);
                    ww = ww < 0 ? 0 : (ww >= W_ ? W_ - 1 : ww);
                }
                const float4 xv = reinterpret_cast<const float4*>(
                    ximg + (((size_t)(hh * W_ + ww)) << 6))[c4i];
                float4 kv = kq[ti * 3 + tj];
                if (!INTERIOR) {
                    kv.x = valid ? kv.x : 0.f;
                    kv.y = valid ? kv.y : 0.f;
                    kv.z = valid ? kv.z : 0.f;
                    kv.w = valid ? kv.w : 0.f;
                }
                acc.x = fmaf(kv.x, xv.x, acc.x);
                acc.y = fmaf(kv.y, xv.y, acc.y);
                acc.z = fmaf(kv.z, xv.z, acc.z);
                acc.w = fmaf(kv.w, xv.w, acc.w);
            }
        }
        reinterpret_cast<float4*>(oimg + (((size_t)(h * W_ + w)) << 6))[c4i] = acc;
    }
}

__global__ __launch_bounds__(256, 8)
void invol_fused(const float* __restrict__ x,
                 const float* __restrict__ w1,
                 const float* __restrict__ b1,
                 const float* __restrict__ gamma,
                 const float* __restrict__ beta,
                 const float* __restrict__ mean,
                 const float* __restrict__ var,
                 const float* __restrict__ w2,
                 const float* __restrict__ b2,
                 float* __restrict__ out)
{
    __shared__ float4 s_t4[NPIX * 4];     // t (16 f32/px)  = 4 KB
    __shared__ float4 s_kern4[NPIX * 9];  // kern (36 f32/px) = 9.2 KB

    const int bid = blockIdx.x;
    // XCD swizzle: 4608 = 8 * 576; each XCD owns one image.
    const int img = bid & 7;
    const int tin = bid >> 3;
    const int th0 = (tin / TILES_X) * TH_;
    const int tw0 = (tin % TILES_X) * TW_;

    const int tid = threadIdx.x;
    const int px  = tid >> 2;   // pixel 0..63 in tile
    const int sub = tid & 3;    // 4 threads per pixel
    const int r = px >> 3, cc = px & 7;
    const int h = th0 + r, w = tw0 + cc;

    // ------------- Phase A1: t = BN(ReLU(x@w1+b1)) ; sub owns td[4*sub..] ---
    {
        const float4* xp = reinterpret_cast<const float4*>(
            x + (((size_t)((img * H_ + h) * W_ + w)) << 6));

        float td[4] = {0.f, 0.f, 0.f, 0.f};
        #pragma unroll
        for (int c4 = 0; c4 < 16; ++c4) {
            const float4 xv = xp[c4];
            const float xs[4] = {xv.x, xv.y, xv.z, xv.w};
            #pragma unroll
            for (int k = 0; k < 4; ++k) {
                // w1 row chunk for this sub: 16B-aligned float4, L1-hot
                const float4 wv4 = reinterpret_cast<const float4*>(
                    w1 + (c4 * 4 + k) * CR_)[sub];
                td[0] = fmaf(xs[k], wv4.x, td[0]);
                td[1] = fmaf(xs[k], wv4.y, td[1]);
                td[2] = fmaf(xs[k], wv4.z, td[2]);
                td[3] = fmaf(xs[k], wv4.w, td[3]);
            }
        }
        #pragma unroll
        for (int d = 0; d < 4; ++d) {
            const int dd = sub * 4 + d;
            const float a = gamma[dd] * rsqrtf(var[dd] + BN_EPS);
            const float c = (b1[dd] - mean[dd]) * a + beta[dd];
            td[d] = fmaxf(fmaf(td[d], a, c), 0.f);
        }
        s_t4[px * 4 + sub] = make_float4(td[0], td[1], td[2], td[3]);
    }
    __syncthreads();

    // ------------- Phase A2: kern = t@w2 + b2 ; sub owns e = sub*9..sub*9+8 -
    {
        float t[16];
        #pragma unroll
        for (int k = 0; k < 4; ++k) {
            const float4 tq = s_t4[px * 4 + k];  // 4-way broadcast read
            t[k * 4 + 0] = tq.x; t[k * 4 + 1] = tq.y;
            t[k * 4 + 2] = tq.z; t[k * 4 + 3] = tq.w;
        }
        float ke[9];
        #pragma unroll
        for (int j = 0; j < 9; ++j) ke[j] = b2[sub * 9 + j];
        #pragma unroll
        for (int d = 0; d < 16; ++d) {
            const float* wr = w2 + d * 36 + sub * 9;  // L1-hot, 4 addrs/instr
            #pragma unroll
            for (int j = 0; j < 9; ++j)
                ke[j] = fmaf(t[d], wr[j], ke[j]);
        }
        // e-linear layout matches Phase B's [px][tap][g] float4 view.
        float* sk = reinterpret_cast<float*>(s_kern4) + px * 36 + sub * 9;
        #pragma unroll
        for (int j = 0; j < 9; ++j) sk[j] = ke[j];
    }
    __syncthreads();

    // ------------- Phase B: 9-tap multiply-reduce ---------------------------
    const bool interior = (th0 > 0) && (th0 + TH_ < H_) &&
                          (tw0 > 0) && (tw0 + TW_ < W_);
    if (interior)
        phase_b<true>(x, out, s_kern4, img, th0, tw0, tid);
    else
        phase_b<false>(x, out, s_kern4, img, th0, tw0, tid);
}

extern "C" void kernel_launch(void* const* d_in, const int* in_sizes, int n_in,
                              void* d_out, int out_size, void* d_ws, size_t ws_size,
                              hipStream_t stream) {
    const float* x     = (const float*)d_in[0];
    const float* w1    = (const float*)d_in[1];
    const float* b1    = (const float*)d_in[2];
    const float* gamma = (const float*)d_in[3];
    const float* beta  = (const float*)d_in[4];
    const float* mean  = (const float*)d_in[5];
    const float* var   = (const float*)d_in[6];
    const float* w2    = (const float*)d_in[7];
    const float* b2    = (const float*)d_in[8];
    float* out = (float*)d_out;

    invol_fused<<<dim3(NBLK), dim3(256), 0, stream>>>(
        x, w1, b1, gamma, beta, mean, var, w2, b2, out);
}

// Round 4
// 198.947 us; speedup vs baseline: 1.1752x; 1.1752x over previous
//
#include <hip/hip_runtime.h>

// Involution (B=8, H=W=192, C=64, G=4, K=3, R=4) — fused, round 4.
// R3 post-mortem: launch_bounds(256,8) -> VGPR=32 -> zero MLP, regressed.
// R4: R2 structure (16x8 tile / 128 thr / scalar weight loads) with
// VGPR cap 128 and a software-pipelined Phase B: next pixel's 9 tap loads
// (xb[9]) issue before current pixel's FMAs (xa[9]) -> ~9 loads in flight
// per wave instead of ~2. Memory floor (97+76 MB @ 6.3 TB/s) ~ 28 us.

#define B_   8
#define H_   192
#define W_   192
#define CR_  16
#define TH_  8
#define TW_  16
#define TILES_X (W_/TW_)                    // 12
#define TILES_PER_IMG (TILES_X*(H_/TH_))    // 288
#define NBLK (B_*TILES_PER_IMG)             // 2304
#define NPIX (TH_*TW_)                      // 128

constexpr float BN_EPS = 1e-3f;

// Load the 9 taps for pixel (h,w), chunk c4i. Addresses are always clamped
// in-bounds (loads never predicated -> they batch); validity mask m9 zeroes
// the kern weight instead (matches zero-padding semantics).
template <bool INTERIOR>
__device__ __forceinline__ void tap_load(const float* __restrict__ ximg,
                                         int h, int w, int c4i,
                                         float4 (&xv)[9], int& m9)
{
    m9 = 0x1FF;
    #pragma unroll
    for (int ti = 0; ti < 3; ++ti) {
        int hh = h + ti - 1;
        bool vh = true;
        if (!INTERIOR) {
            vh = (unsigned)hh < (unsigned)H_;
            hh = hh < 0 ? 0 : (hh >= H_ ? H_ - 1 : hh);
        }
        #pragma unroll
        for (int tj = 0; tj < 3; ++tj) {
            int ww = w + tj - 1;
            if (!INTERIOR) {
                const bool v = vh && ((unsigned)ww < (unsigned)W_);
                ww = ww < 0 ? 0 : (ww >= W_ ? W_ - 1 : ww);
                if (!v) m9 &= ~(1 << (ti * 3 + tj));
            }
            xv[ti * 3 + tj] = reinterpret_cast<const float4*>(
                ximg + (((size_t)(hh * W_ + ww)) << 6))[c4i];
        }
    }
}

template <bool INTERIOR>
__device__ __forceinline__ void phase_b(const float* __restrict__ x,
                                        float* __restrict__ out,
                                        const float4* __restrict__ s_kern,
                                        int img, int th0, int tw0, int tid)
{
    const int prow = tid >> 4;   // 0..7 (pixel slot across both waves)
    const int c4i  = tid & 15;   // float4 channel chunk (g = 0..3 inside)
    const float* ximg = x + (((size_t)(img * H_ * W_)) << 6);
    float* oimg = out + (((size_t)(img * H_ * W_)) << 6);

    // Pixel for iteration i: q = i*8 + prow; 16-lane groups cover 4 adjacent
    // pixels x 16 chunks = 1 KB contiguous per wave load/store instruction.
    auto hw_of = [&](int i, int& h, int& w, int& q) {
        q = i * 8 + prow;
        h = th0 + (q >> 4);
        w = tw0 + (q & 15);
    };

    // --- software pipeline: prologue loads for i=0 ---
    float4 xa[9]; int ma;
    {
        int h, w, q;
        hw_of(0, h, w, q);
        tap_load<INTERIOR>(ximg, h, w, c4i, xa, ma);
    }

    for (int i = 0; i < 16; ++i) {
        // prefetch next pixel's taps (issues before current FMAs wait)
        float4 xb[9]; int mb = 0x1FF;
        if (i + 1 < 16) {
            int hn, wn, qn;
            hw_of(i + 1, hn, wn, qn);
            tap_load<INTERIOR>(ximg, hn, wn, c4i, xb, mb);
        }

        int h, w, q;
        hw_of(i, h, w, q);
        const float4* kq = &s_kern[q * 9];

        float4 acc = make_float4(0.f, 0.f, 0.f, 0.f);
        #pragma unroll
        for (int t = 0; t < 9; ++t) {
            float4 kv = kq[t];
            if (!INTERIOR) {
                const bool v = (ma >> t) & 1;
                kv.x = v ? kv.x : 0.f;
                kv.y = v ? kv.y : 0.f;
                kv.z = v ? kv.z : 0.f;
                kv.w = v ? kv.w : 0.f;
            }
            acc.x = fmaf(kv.x, xa[t].x, acc.x);
            acc.y = fmaf(kv.y, xa[t].y, acc.y);
            acc.z = fmaf(kv.z, xa[t].z, acc.z);
            acc.w = fmaf(kv.w, xa[t].w, acc.w);
        }
        reinterpret_cast<float4*>(oimg + (((size_t)(h * W_ + w)) << 6))[c4i] = acc;

        // rotate buffers (register renames, free)
        #pragma unroll
        for (int t = 0; t < 9; ++t) xa[t] = xb[t];
        ma = mb;
    }
}

__global__ __launch_bounds__(128, 4)
void invol_fused(const float* __restrict__ x,
                 const float* __restrict__ w1,
                 const float* __restrict__ b1,
                 const float* __restrict__ gamma,
                 const float* __restrict__ beta,
                 const float* __restrict__ mean,
                 const float* __restrict__ var,
                 const float* __restrict__ w2,
                 const float* __restrict__ b2,
                 float* __restrict__ out)
{
    // 128 pixels * 9 float4 (36 kern floats, tap-major, g minor) = 18 KB
    __shared__ float4 s_kern[NPIX * 9];

    const int bid = blockIdx.x;
    // XCD swizzle: 2304 = 8 * 288; each XCD owns one image for L2 locality.
    const int img = bid & 7;
    const int tin = bid >> 3;
    const int th0 = (tin / TILES_X) * TH_;
    const int tw0 = (tin % TILES_X) * TW_;

    const int tid = threadIdx.x;

    // ---------------- Phase A: kernel generation (1 thread = 1 pixel) -------
    {
        const int r = tid >> 4, cc = tid & 15;
        const int h = th0 + r, w = tw0 + cc;
        const float4* xp = reinterpret_cast<const float4*>(
            x + (((size_t)((img * H_ + h) * W_ + w)) << 6));

        float td[CR_];
        #pragma unroll
        for (int d = 0; d < CR_; ++d) td[d] = 0.f;

        // t = x @ w1   (weight addresses wave-uniform -> s_load, SMEM pipe)
        #pragma unroll
        for (int c4 = 0; c4 < 16; ++c4) {
            const float4 xv = xp[c4];
            const float xs[4] = {xv.x, xv.y, xv.z, xv.w};
            #pragma unroll
            for (int k = 0; k < 4; ++k) {
                const float* wr = w1 + (c4 * 4 + k) * CR_;
                #pragma unroll
                for (int d = 0; d < CR_; ++d)
                    td[d] = fmaf(xs[k], wr[d], td[d]);
            }
        }

        // + b1, BN (inference), ReLU — folded affine
        #pragma unroll
        for (int d = 0; d < CR_; ++d) {
            const float a = gamma[d] * rsqrtf(var[d] + BN_EPS);
            const float c = (b1[d] - mean[d]) * a + beta[d];
            td[d] = fmaxf(fmaf(td[d], a, c), 0.f);
        }

        // kern = t @ w2 + b2  (e = tap*4 + g)
        float ke[36];
        #pragma unroll
        for (int e = 0; e < 36; ++e) ke[e] = b2[e];
        #pragma unroll
        for (int d = 0; d < CR_; ++d) {
            const float t = td[d];
            const float* wr = w2 + d * 36;
            #pragma unroll
            for (int e = 0; e < 36; ++e)
                ke[e] = fmaf(t, wr[e], ke[e]);
        }

        // stride 36 words (144 B): conflict-free b128 (measured 0 conflicts)
        float4* skq = &s_kern[tid * 9];
        #pragma unroll
        for (int t9 = 0; t9 < 9; ++t9)
            skq[t9] = make_float4(ke[t9 * 4 + 0], ke[t9 * 4 + 1],
                                  ke[t9 * 4 + 2], ke[t9 * 4 + 3]);
    }

    __syncthreads();

    // ---------------- Phase B: 9-tap multiply-reduce ------------------------
    const bool interior = (th0 > 0) && (th0 + TH_ < H_) &&
                          (tw0 > 0) && (tw0 + TW_ < W_);
    if (interior)
        phase_b<true>(x, out, s_kern, img, th0, tw0, tid);
    else
        phase_b<false>(x, out, s_kern, img, th0, tw0, tid);
}

extern "C" void kernel_launch(void* const* d_in, const int* in_sizes, int n_in,
                              void* d_out, int out_size, void* d_ws, size_t ws_size,
                              hipStream_t stream) {
    const float* x     = (const float*)d_in[0];
    const float* w1    = (const float*)d_in[1];
    const float* b1    = (const float*)d_in[2];
    const float* gamma = (const float*)d_in[3];
    const float* beta  = (const float*)d_in[4];
    const float* mean  = (const float*)d_in[5];
    const float* var   = (const float*)d_in[6];
    const float* w2    = (const float*)d_in[7];
    const float* b2    = (const float*)d_in[8];
    float* out = (float*)d_out;

    invol_fused<<<dim3(NBLK), dim3(128), 0, stream>>>(
        x, w1, b1, gamma, beta, mean, var, w2, b2, out);
}